// Round 17
// baseline (3962.800 us; speedup 1.0000x reference)
//
#include <hip/hip_runtime.h>

#define HDIM 2048   // LSTM_DIM
#define G4   8192   // 4*HDIM
#define NB   64     // BATCH
#define NT   512    // MAX_STEPS
#define MEL  512
#define KIN  512    // INPUT_SIZE
#define NWG  256    // 2 domains x 128
#define NBH  (NB * HDIM)
#define NSLOT 512   // per (domain,stream): 128 WGs x 4 reducer waves

typedef __attribute__((ext_vector_type(8))) short short8;
typedef __attribute__((ext_vector_type(4))) float f32x4;
typedef __attribute__((ext_vector_type(4))) unsigned uint32x4;

__device__ __forceinline__ unsigned short f2bf(float f){
  union { float f; unsigned u; } v; v.f = f;
  return (unsigned short)((v.u + 0x7fffu + ((v.u >> 16) & 1u)) >> 16);
}
__device__ __forceinline__ float sigm(float x){ return 1.f / (1.f + __expf(-x)); }
__device__ __forceinline__ float tanhfast(float x){ return 1.f - 2.f / (__expf(2.f * x) + 1.f); }

__device__ __forceinline__ f32x4 MF(short8 a, short8 b, f32x4 c){
  return __builtin_amdgcn_mfma_f32_16x16x32_bf16(a, b, c, 0, 0, 0);
}
__device__ __forceinline__ short8 as8(uint32x4 u){
  union { uint32x4 u; short8 s; } x; x.u = u; return x.s;
}
// h load: RING -> plain cached (fresh addresses per step => no staleness; per-XCD L2
// fans out the broadcast). !RING -> IC bypass (R8-proven fallback).
template<bool RING>
__device__ __forceinline__ void ldh(uint32x4& d, const unsigned short* p){
  if constexpr (RING)
    asm volatile("global_load_dwordx4 %0, %1, off"
                 : "=&v"(d) : "v"(p) : "memory");
  else
    asm volatile("global_load_dwordx4 %0, %1, off sc0 sc1"
                 : "=&v"(d) : "v"(p) : "memory");
}

// ---------------- fp32 -> bf16 convert ----------------
__global__ void convert_kernel(const float* __restrict__ src, unsigned short* __restrict__ dst, int n4){
  int stride = gridDim.x * blockDim.x;
  for (int i = blockIdx.x * blockDim.x + threadIdx.x; i < n4; i += stride){
    const float4 v = *(const float4*)(src + (size_t)i * 4);
    uint2 pk;
    pk.x = (unsigned)f2bf(v.x) | ((unsigned)f2bf(v.y) << 16);
    pk.y = (unsigned)f2bf(v.z) | ((unsigned)f2bf(v.w) << 16);
    *(uint2*)(dst + (size_t)i * 4) = pk;
  }
}

// ---------------- b_eff = b_ih + b_hh + W_ih @ b_out ----------------
__global__ void beff_kernel(const float* __restrict__ W_ih, const float* __restrict__ b_ih,
                            const float* __restrict__ b_hh, const float* __restrict__ b_out,
                            float* __restrict__ b_eff){
  int r = blockIdx.x;
  int lane = threadIdx.x;  // 64 threads = 1 wave
  float acc = 0.f;
  for (int k = lane; k < KIN; k += 64) acc += W_ih[(size_t)r * KIN + k] * b_out[k];
  #pragma unroll
  for (int off = 32; off > 0; off >>= 1) acc += __shfl_down(acc, off, 64);
  if (lane == 0) b_eff[r] = b_ih[r] + b_hh[r] + acc;
}

// ---------------- ym1[b][m] = Wout[m]·h0[b] + b_out[m] ----------------
__global__ void ym1_kernel(const float* __restrict__ Wout, const float* __restrict__ h0,
                           const float* __restrict__ b_out, float* __restrict__ ym1){
  const int b = blockIdx.x;
  const int m = blockIdx.y * 64 + threadIdx.x;
  const float* wr = Wout + (size_t)m * HDIM;
  const float* hr = h0 + (size_t)b * HDIM;
  float a0 = 0.f, a1 = 0.f, a2 = 0.f, a3 = 0.f;
  for (int k = 0; k < HDIM; k += 4){
    const float4 wv = *(const float4*)(wr + k);
    const float4 hv = *(const float4*)(hr + k);
    a0 += wv.x * hv.x; a1 += wv.y * hv.y; a2 += wv.z * hv.z; a3 += wv.w * hv.w;
  }
  ym1[(size_t)b * MEL + m] = a0 + a1 + a2 + a3 + b_out[m];
}

// ---------------- corr[r][b] = W_ih[r]·ym1[b] ----------------
__global__ void corr_kernel(const float* __restrict__ Wih, const float* __restrict__ ym1,
                            float* __restrict__ corr){
  const int r = blockIdx.x;
  const int b = threadIdx.x;
  const float* wr = Wih + (size_t)r * KIN;
  const float* yr = ym1 + (size_t)b * MEL;
  float a0 = 0.f, a1 = 0.f, a2 = 0.f, a3 = 0.f;
  for (int m = 0; m < KIN; m += 4){
    const float4 wv = *(const float4*)(wr + m);
    const float4 yv = *(const float4*)(yr + m);
    a0 += wv.x * yv.x; a1 += wv.y * yv.y; a2 += wv.z * yv.z; a3 += wv.w * yv.w;
  }
  corr[(size_t)r * NB + b] = a0 + a1 + a2 + a3;
}

// ---------------- W_eff = bf16( W_hh + W_ih @ W_out )  [8192 x 2048], K=512 ----------------
__global__ __launch_bounds__(256) void weff_gemm(const float* __restrict__ W_ih, const float* __restrict__ W_out,
                                                 const float* __restrict__ W_hh, unsigned short* __restrict__ Weff){
  __shared__ __align__(16) float As[32][68];  // [k][m]
  __shared__ __align__(16) float Bs[32][68];  // [k][n]
  const int bn = blockIdx.x * 64;
  const int bm = blockIdx.y * 64;
  const int t = threadIdx.x;
  const int tx = t & 15, ty = t >> 4;
  float acc[4][4] = {};
  for (int k0 = 0; k0 < KIN; k0 += 32){
    #pragma unroll
    for (int i = 0; i < 2; i++){
      int f = t + i * 256;
      int row = f >> 3, c4 = (f & 7) * 4;
      const float4 v = *(const float4*)(W_ih + (size_t)(bm + row) * KIN + k0 + c4);
      As[c4 + 0][row] = v.x; As[c4 + 1][row] = v.y; As[c4 + 2][row] = v.z; As[c4 + 3][row] = v.w;
    }
    #pragma unroll
    for (int i = 0; i < 2; i++){
      int f = t + i * 256;
      int kr = f >> 4, c4 = (f & 15) * 4;
      *(float4*)&Bs[kr][c4] = *(const float4*)(W_out + (size_t)(k0 + kr) * HDIM + bn + c4);
    }
    __syncthreads();
    #pragma unroll
    for (int kk = 0; kk < 32; kk++){
      const float4 av = *(const float4*)&As[kk][ty * 4];
      const float4 bv = *(const float4*)&Bs[kk][tx * 4];
      const float ar[4] = {av.x, av.y, av.z, av.w};
      const float br[4] = {bv.x, bv.y, bv.z, bv.w};
      #pragma unroll
      for (int i = 0; i < 4; i++)
        #pragma unroll
        for (int j = 0; j < 4; j++)
          acc[i][j] += ar[i] * br[j];
    }
    __syncthreads();
  }
  #pragma unroll
  for (int i = 0; i < 4; i++){
    const size_t row = (size_t)bm + ty * 4 + i;
    const float4 wh = *(const float4*)(W_hh + row * HDIM + bn + tx * 4);
    uint2 pk;
    pk.x = (unsigned)f2bf(acc[i][0] + wh.x) | ((unsigned)f2bf(acc[i][1] + wh.y) << 16);
    pk.y = (unsigned)f2bf(acc[i][2] + wh.z) | ((unsigned)f2bf(acc[i][3] + wh.w) << 16);
    *(uint2*)(Weff + row * HDIM + bn + tx * 4) = pk;
  }
}

// ---------------- per-WAVE wait on PRODUCER SUBSET: 64 slots (1 dword/lane) ----------------
// Consumer wave v consumes h[k], k in [256v,256v+256) -> produced by WGs jg in
// [16v,16v+16) x 4 reducer waves = slots [64v, 64v+64).
__device__ __forceinline__ void wait64(const unsigned* __restrict__ base, int lane, unsigned tgt){
  const unsigned* sp = base + lane;
  while (true){
    unsigned vv;
    asm volatile("global_load_dword %0, %1, off sc0 sc1\n\t"
                 "s_waitcnt vmcnt(0)"
                 : "=v"(vv) : "v"(sp) : "memory");
    if (__all((int)(vv >= tgt))) break;
    __builtin_amdgcn_s_sleep(1);
  }
}

// ---------------- persistent decoder: R13 + 8-chunk load preload ----------------
// Domain d owns batches [32d,32d+32) (2 sub-streams of 16). WG (d,jg) owns j-cols
// [16jg,16jg+16); weights in regs (wave v = k-slice [256v,256v+256)).
// Per sub-step: per-wave wait (64 producer slots) -> ALL 8 h-chunk loads issued up
// front (8 buffers, +16 VGPR; FETCH_SIZE tripwire guards weight residency) ->
// WAITV(7..0) descending -> MFMA -> sync -> exchange -> sync -> reduce (waves 0-3)
// with per-wave drain + slot post (no trailing WG sync; waves 4-7 run ahead).
#define LDSX (16384*4 + 512*4)

template<bool RING>
__global__ void __launch_bounds__(512, 1) decoder_coop(
    const unsigned short* __restrict__ Weff_b,
    const unsigned short* __restrict__ Wout_b,
    const float* __restrict__ b_eff,
    const float* __restrict__ corr,
    const float* __restrict__ c0,
    const float* __restrict__ b_out,
    unsigned short* __restrict__ hring,  // [RING?NT+1:2][64][2048] bf16; slot0 = bf16(h0)
    unsigned* __restrict__ slots,        // [2][2][512] zeroed
    float* __restrict__ out)             // [64][512][512]
{
  extern __shared__ char smem[];
  float* exf = (float*)smem;             // 16384 floats
  float* eyf = exf + 16384;              // 512 floats
  const int bid  = blockIdx.x;
  const int d    = bid & 1;              // domain (interleaved across XCDs)
  const int jg   = bid >> 1;             // j-group 0..127
  const int tid  = threadIdx.x;
  const int v    = tid >> 6;             // wave = k-slice owner
  const int lane = tid & 63;
  const int col  = lane & 15;
  const int q    = lane >> 4;
  const int kbase = v * 256;

  // ---- A-fragment preload into regs: 4 gate tiles + y tile ----
  short8 A0[8], A1[8], A2[8], A3[8], Ay[8];
  #pragma unroll
  for (int it = 0; it < 8; ++it){
    const size_t kc = (size_t)kbase + it * 32 + q * 8;
    A0[it] = *(const short8*)(Weff_b + (size_t)(0 * HDIM + jg * 16 + col) * HDIM + kc);
    A1[it] = *(const short8*)(Weff_b + (size_t)(1 * HDIM + jg * 16 + col) * HDIM + kc);
    A2[it] = *(const short8*)(Weff_b + (size_t)(2 * HDIM + jg * 16 + col) * HDIM + kc);
    A3[it] = *(const short8*)(Weff_b + (size_t)(3 * HDIM + jg * 16 + col) * HDIM + kc);
    if (col < 4)
      Ay[it] = *(const short8*)(Wout_b + (size_t)(jg * 4 + col) * HDIM + kc);
    else { short8 z = {0,0,0,0,0,0,0,0}; Ay[it] = z; }
  }

  // ---- reducer constants: tid<256 -> (jl, bs); per-stream c-state ----
  const int jl = tid & 15;
  const int bs = tid >> 4;               // 0..15 for tid<256
  const int rj = jg * 16 + jl;
  float be0 = 0.f, be1 = 0.f, be2 = 0.f, be3 = 0.f;
  float cs_s0 = 0.f, cs_s1 = 0.f;
  if (tid < 256){
    be0 = b_eff[0 * HDIM + rj]; be1 = b_eff[1 * HDIM + rj];
    be2 = b_eff[2 * HDIM + rj]; be3 = b_eff[3 * HDIM + rj];
    cs_s0 = c0[(size_t)(d * 32 + bs) * HDIM + rj];
    cs_s1 = c0[(size_t)(d * 32 + 16 + bs) * HDIM + rj];
  }
  const bool isY = (tid >= 256 && tid < 320);
  float byo = 0.f; int yr = 0, ybs = 0;
  if (isY){ const int yt = tid - 256; yr = yt & 3; ybs = yt >> 2; byo = b_out[jg * 4 + yr]; }

  // per-lane B element-offsets per stream
  int boff[2];
  #pragma unroll
  for (int s = 0; s < 2; ++s)
    boff[s] = (d * 32 + s * 16 + col) * HDIM + kbase + q * 8;

#define WAITV(N) asm volatile("s_waitcnt vmcnt(" #N ")" ::: "memory"); __builtin_amdgcn_sched_barrier(0);
#define MFM(IT, G) { \
    const short8 bv = as8(G); \
    a0 = MF(A0[IT], bv, a0); a1 = MF(A1[IT], bv, a1); \
    a2 = MF(A2[IT], bv, a2); a3 = MF(A3[IT], bv, a3); \
    ay = MF(Ay[IT], bv, ay); }

  for (int t = 0; t < NT; ++t){
    #pragma unroll
    for (int s = 0; s < 2; ++s){
      unsigned* slot_ds = slots + (d * 2 + s) * NSLOT;
      if (t) wait64(slot_ds + 64 * v, lane, (unsigned)t);   // producer subset only

      const unsigned short* hcur = hring + (size_t)(RING ? t : (t & 1)) * NBH;
      const int bo = boff[s];
      uint32x4 P0, P1, P2, P3, P4, P5, P6, P7;
      f32x4 a0 = {0,0,0,0}, a1 = {0,0,0,0}, a2 = {0,0,0,0}, a3 = {0,0,0,0}, ay = {0,0,0,0};

      ldh<RING>(P0, hcur + bo);
      ldh<RING>(P1, hcur + bo + 32);
      ldh<RING>(P2, hcur + bo + 64);
      ldh<RING>(P3, hcur + bo + 96);
      ldh<RING>(P4, hcur + bo + 128);
      ldh<RING>(P5, hcur + bo + 160);
      ldh<RING>(P6, hcur + bo + 192);
      ldh<RING>(P7, hcur + bo + 224);
      WAITV(7) MFM(0, P0)
      WAITV(6) MFM(1, P1)
      WAITV(5) MFM(2, P2)
      WAITV(4) MFM(3, P3)
      WAITV(3) MFM(4, P4)
      WAITV(2) MFM(5, P5)
      WAITV(1) MFM(6, P6)
      WAITV(0) MFM(7, P7)

      __syncthreads();   // #1: previous sub-step's reduce done -> exf/eyf reusable

      // ---- exchange stores: pitch 32, swizzle col^((lr&7)<<2) (bijective in-row) ----
      #pragma unroll
      for (int e = 0; e < 4; ++e){
        const int lr = q * 4 + e;
        const int cx = col ^ ((lr & 7) << 2);
        exf[(v * 64 +  0 + lr) * 32 + cx] = a0[e];
        exf[(v * 64 + 16 + lr) * 32 + cx] = a1[e];
        exf[(v * 64 + 32 + lr) * 32 + cx] = a2[e];
        exf[(v * 64 + 48 + lr) * 32 + cx] = a3[e];
      }
      if (q == 0){
        #pragma unroll
        for (int e = 0; e < 4; ++e) eyf[(v * 4 + e) * 16 + col] = ay[e];
      }
      __syncthreads();   // #2: exchange visible

      if (tid < 256){
        const int cidx = bs ^ ((jl & 7) << 2);
        float gi = 0.f, gf = 0.f, gg = 0.f, go = 0.f;
        #pragma unroll
        for (int vv = 0; vv < 8; ++vv){
          gi += exf[(vv * 64 +  0 + jl) * 32 + cidx];
          gf += exf[(vv * 64 + 16 + jl) * 32 + cidx];
          gg += exf[(vv * 64 + 32 + jl) * 32 + cidx];
          go += exf[(vv * 64 + 48 + jl) * 32 + cidx];
        }
        const int b = d * 32 + s * 16 + bs;
        gi += be0; gf += be1; gg += be2; go += be3;
        if (t == 0){
          gi -= corr[(size_t)(0 * HDIM + rj) * NB + b];
          gf -= corr[(size_t)(1 * HDIM + rj) * NB + b];
          gg -= corr[(size_t)(2 * HDIM + rj) * NB + b];
          go -= corr[(size_t)(3 * HDIM + rj) * NB + b];
        }
        float cs = s ? cs_s1 : cs_s0;
        const float i_ = sigm(gi), f_ = sigm(gf), g_ = tanhfast(gg), o_ = sigm(go);
        cs = f_ * cs + i_ * g_;
        const float hn = o_ * tanhfast(cs);
        if (s) cs_s1 = cs; else cs_s0 = cs;

        // pack adjacent jl via shfl, 4B agent-scope store to IC
        const float pn = __shfl_xor(hn, 1, 64);
        unsigned short* hdst = hring + (size_t)(RING ? (t + 1) : ((t + 1) & 1)) * NBH;
        if ((jl & 1) == 0){
          const unsigned pk = (unsigned)f2bf(hn) | ((unsigned)f2bf(pn) << 16);
          __hip_atomic_store((unsigned*)(hdst + (size_t)b * HDIM + rj), pk,
                             __ATOMIC_RELAXED, __HIP_MEMORY_SCOPE_AGENT);
        }
        // per-wave arrival: own h stores drained -> post this wave's slot
        asm volatile("s_waitcnt vmcnt(0)" ::: "memory");
        __builtin_amdgcn_sched_barrier(0);
        if (lane == 0)
          __hip_atomic_store(slot_ds + (jg << 2) + v, (unsigned)(t + 1),
                             __ATOMIC_RELAXED, __HIP_MEMORY_SCOPE_AGENT);
      } else if (isY && t >= 1){
        float yv = byo;
        #pragma unroll
        for (int vv = 0; vv < 8; ++vv) yv += eyf[(vv * 4 + yr) * 16 + ybs];
        const int b = d * 32 + s * 16 + ybs;
        out[((size_t)b * NT + (t - 1)) * MEL + jg * 4 + yr] = yv;
      }
      // no trailing WG sync: non-reducer waves run ahead into the next sub-step
    }
  }

  // ---- final frame: y_511 = h_512 @ Wout^T + b_out ----
  #pragma unroll
  for (int s = 0; s < 2; ++s){
    wait64(slots + (d * 2 + s) * NSLOT + 64 * v, lane, (unsigned)NT);
    const unsigned short* hfin = hring + (size_t)(RING ? NT : 0) * NBH;  // NT even
    const int bo = boff[s];
    f32x4 ay = {0,0,0,0};
    #pragma unroll
    for (int it = 0; it < 8; ++it){
      uint32x4 g;
      ldh<RING>(g, hfin + bo + it * 32);
      asm volatile("s_waitcnt vmcnt(0)" ::: "memory");
      __builtin_amdgcn_sched_barrier(0);
      ay = MF(Ay[it], as8(g), ay);
    }
    __syncthreads();   // prior eyf readers (main loop / prev s) done
    if (q == 0){
      #pragma unroll
      for (int e = 0; e < 4; ++e) eyf[(v * 4 + e) * 16 + col] = ay[e];
    }
    __syncthreads();
    if (isY){
      float yv = byo;
      #pragma unroll
      for (int vv = 0; vv < 8; ++vv) yv += eyf[(vv * 4 + yr) * 16 + ybs];
      const int b = d * 32 + s * 16 + ybs;
      out[((size_t)b * NT + 511) * MEL + jg * 4 + yr] = yv;
    }
    __syncthreads();
  }
}

extern "C" void kernel_launch(void* const* d_in, const int* in_sizes, int n_in,
                              void* d_out, int out_size, void* d_ws, size_t ws_size,
                              hipStream_t stream){
  (void)in_sizes; (void)n_in; (void)out_size;
  const float* h0    = (const float*)d_in[1];
  const float* c0    = (const float*)d_in[2];
  const float* W_ih  = (const float*)d_in[3];
  const float* W_hh  = (const float*)d_in[4];
  const float* b_ih  = (const float*)d_in[5];
  const float* b_hh  = (const float*)d_in[6];
  const float* W_out = (const float*)d_in[7];
  const float* b_out = (const float*)d_in[8];
  float* out = (float*)d_out;

  const size_t fixed = (size_t)G4 * HDIM * 2      // weff
                     + (size_t)MEL * HDIM * 2     // wout
                     + (size_t)G4 * 4             // beff
                     + (size_t)G4 * NB * 4        // corr
                     + (size_t)NB * MEL * 4       // ym1
                     + 4 * NSLOT * sizeof(unsigned) // slots
                     + 1024;
  const bool ring = ws_size >= fixed + (size_t)(NT + 1) * NBH * 2;
  const int hslots = ring ? (NT + 1) : 2;

  char* p = (char*)d_ws;
  unsigned short* weff_b = (unsigned short*)p; p += (size_t)G4 * HDIM * 2;   // 33.5 MB
  unsigned short* wout_b = (unsigned short*)p; p += (size_t)MEL * HDIM * 2;  // 2 MB
  float* beff = (float*)p;  p += (size_t)G4 * 4;
  float* corr = (float*)p;  p += (size_t)G4 * NB * 4;                        // 2 MB
  float* ym1  = (float*)p;  p += (size_t)NB * MEL * 4;                       // 128 KB
  unsigned* slots = (unsigned*)p; p += 4 * NSLOT * sizeof(unsigned);
  unsigned short* hring = (unsigned short*)p; p += (size_t)hslots * NBH * 2;

  hipMemsetAsync(slots, 0, 4 * NSLOT * sizeof(unsigned), stream);
  convert_kernel<<<256, 256, 0, stream>>>(W_out, wout_b, MEL * HDIM / 4);
  convert_kernel<<<64, 256, 0, stream>>>(h0, hring, NBH / 4);
  beff_kernel<<<G4, 64, 0, stream>>>(W_ih, b_ih, b_hh, b_out, beff);
  ym1_kernel<<<dim3(NB, MEL / 64), 64, 0, stream>>>(W_out, h0, b_out, ym1);
  corr_kernel<<<G4, NB, 0, stream>>>(W_ih, ym1, corr);
  weff_gemm<<<dim3(HDIM / 64, G4 / 64), 256, 0, stream>>>(W_ih, W_out, W_hh, weff_b);

  void* kargs[] = { (void*)&weff_b, (void*)&wout_b, (void*)&beff, (void*)&corr,
                    (void*)&c0, (void*)&b_out, (void*)&hring, (void*)&slots, (void*)&out };
  if (ring){
    hipFuncSetAttribute((const void*)decoder_coop<true>,
                        hipFuncAttributeMaxDynamicSharedMemorySize, LDSX);
    hipLaunchCooperativeKernel((const void*)decoder_coop<true>, dim3(NWG), dim3(512),
                               kargs, LDSX, stream);
  } else {
    hipFuncSetAttribute((const void*)decoder_coop<false>,
                        hipFuncAttributeMaxDynamicSharedMemorySize, LDSX);
    hipLaunchCooperativeKernel((const void*)decoder_coop<false>, dim3(NWG), dim3(512),
                               kargs, LDSX, stream);
  }
}

// Round 18
// 3795.108 us; speedup vs baseline: 1.0442x; 1.0442x over previous
//
#include <hip/hip_runtime.h>

#define HDIM 2048   // LSTM_DIM
#define G4   8192   // 4*HDIM
#define NB   64     // BATCH
#define NT   512    // MAX_STEPS
#define MEL  512
#define KIN  512    // INPUT_SIZE
#define NWG  256    // 2 domains x 128
#define NBH  (NB * HDIM)
#define NSLOT 512   // per (domain,stream): 128 WGs x 4 reducer waves

typedef __attribute__((ext_vector_type(8))) short short8;
typedef __attribute__((ext_vector_type(4))) float f32x4;
typedef __attribute__((ext_vector_type(4))) unsigned uint32x4;

__device__ __forceinline__ unsigned short f2bf(float f){
  union { float f; unsigned u; } v; v.f = f;
  return (unsigned short)((v.u + 0x7fffu + ((v.u >> 16) & 1u)) >> 16);
}
__device__ __forceinline__ float sigm(float x){ return 1.f / (1.f + __expf(-x)); }
__device__ __forceinline__ float tanhfast(float x){ return 1.f - 2.f / (__expf(2.f * x) + 1.f); }

__device__ __forceinline__ f32x4 MF(short8 a, short8 b, f32x4 c){
  return __builtin_amdgcn_mfma_f32_16x16x32_bf16(a, b, c, 0, 0, 0);
}
__device__ __forceinline__ short8 as8(uint32x4 u){
  union { uint32x4 u; short8 s; } x; x.u = u; return x.s;
}
// h load: RING -> plain cached (fresh addresses per step => no staleness; per-XCD L2
// fans out the broadcast). !RING -> IC bypass (R8-proven fallback).
template<bool RING>
__device__ __forceinline__ void ldh(uint32x4& d, const unsigned short* p){
  if constexpr (RING)
    asm volatile("global_load_dwordx4 %0, %1, off"
                 : "=&v"(d) : "v"(p) : "memory");
  else
    asm volatile("global_load_dwordx4 %0, %1, off sc0 sc1"
                 : "=&v"(d) : "v"(p) : "memory");
}

// ---------------- fp32 -> bf16 convert ----------------
__global__ void convert_kernel(const float* __restrict__ src, unsigned short* __restrict__ dst, int n4){
  int stride = gridDim.x * blockDim.x;
  for (int i = blockIdx.x * blockDim.x + threadIdx.x; i < n4; i += stride){
    const float4 v = *(const float4*)(src + (size_t)i * 4);
    uint2 pk;
    pk.x = (unsigned)f2bf(v.x) | ((unsigned)f2bf(v.y) << 16);
    pk.y = (unsigned)f2bf(v.z) | ((unsigned)f2bf(v.w) << 16);
    *(uint2*)(dst + (size_t)i * 4) = pk;
  }
}

// ---------------- b_eff = b_ih + b_hh + W_ih @ b_out ----------------
__global__ void beff_kernel(const float* __restrict__ W_ih, const float* __restrict__ b_ih,
                            const float* __restrict__ b_hh, const float* __restrict__ b_out,
                            float* __restrict__ b_eff){
  int r = blockIdx.x;
  int lane = threadIdx.x;  // 64 threads = 1 wave
  float acc = 0.f;
  for (int k = lane; k < KIN; k += 64) acc += W_ih[(size_t)r * KIN + k] * b_out[k];
  #pragma unroll
  for (int off = 32; off > 0; off >>= 1) acc += __shfl_down(acc, off, 64);
  if (lane == 0) b_eff[r] = b_ih[r] + b_hh[r] + acc;
}

// ---------------- ym1[b][m] = Wout[m]·h0[b] + b_out[m] ----------------
__global__ void ym1_kernel(const float* __restrict__ Wout, const float* __restrict__ h0,
                           const float* __restrict__ b_out, float* __restrict__ ym1){
  const int b = blockIdx.x;
  const int m = blockIdx.y * 64 + threadIdx.x;
  const float* wr = Wout + (size_t)m * HDIM;
  const float* hr = h0 + (size_t)b * HDIM;
  float a0 = 0.f, a1 = 0.f, a2 = 0.f, a3 = 0.f;
  for (int k = 0; k < HDIM; k += 4){
    const float4 wv = *(const float4*)(wr + k);
    const float4 hv = *(const float4*)(hr + k);
    a0 += wv.x * hv.x; a1 += wv.y * hv.y; a2 += wv.z * hv.z; a3 += wv.w * hv.w;
  }
  ym1[(size_t)b * MEL + m] = a0 + a1 + a2 + a3 + b_out[m];
}

// ---------------- corr[r][b] = W_ih[r]·ym1[b] ----------------
__global__ void corr_kernel(const float* __restrict__ Wih, const float* __restrict__ ym1,
                            float* __restrict__ corr){
  const int r = blockIdx.x;
  const int b = threadIdx.x;
  const float* wr = Wih + (size_t)r * KIN;
  const float* yr = ym1 + (size_t)b * MEL;
  float a0 = 0.f, a1 = 0.f, a2 = 0.f, a3 = 0.f;
  for (int m = 0; m < KIN; m += 4){
    const float4 wv = *(const float4*)(wr + m);
    const float4 yv = *(const float4*)(yr + m);
    a0 += wv.x * yv.x; a1 += wv.y * yv.y; a2 += wv.z * yv.z; a3 += wv.w * yv.w;
  }
  corr[(size_t)r * NB + b] = a0 + a1 + a2 + a3;
}

// ---------------- W_eff = bf16( W_hh + W_ih @ W_out )  [8192 x 2048], K=512 ----------------
__global__ __launch_bounds__(256) void weff_gemm(const float* __restrict__ W_ih, const float* __restrict__ W_out,
                                                 const float* __restrict__ W_hh, unsigned short* __restrict__ Weff){
  __shared__ __align__(16) float As[32][68];  // [k][m]
  __shared__ __align__(16) float Bs[32][68];  // [k][n]
  const int bn = blockIdx.x * 64;
  const int bm = blockIdx.y * 64;
  const int t = threadIdx.x;
  const int tx = t & 15, ty = t >> 4;
  float acc[4][4] = {};
  for (int k0 = 0; k0 < KIN; k0 += 32){
    #pragma unroll
    for (int i = 0; i < 2; i++){
      int f = t + i * 256;
      int row = f >> 3, c4 = (f & 7) * 4;
      const float4 v = *(const float4*)(W_ih + (size_t)(bm + row) * KIN + k0 + c4);
      As[c4 + 0][row] = v.x; As[c4 + 1][row] = v.y; As[c4 + 2][row] = v.z; As[c4 + 3][row] = v.w;
    }
    #pragma unroll
    for (int i = 0; i < 2; i++){
      int f = t + i * 256;
      int kr = f >> 4, c4 = (f & 15) * 4;
      *(float4*)&Bs[kr][c4] = *(const float4*)(W_out + (size_t)(k0 + kr) * HDIM + bn + c4);
    }
    __syncthreads();
    #pragma unroll
    for (int kk = 0; kk < 32; kk++){
      const float4 av = *(const float4*)&As[kk][ty * 4];
      const float4 bv = *(const float4*)&Bs[kk][tx * 4];
      const float ar[4] = {av.x, av.y, av.z, av.w};
      const float br[4] = {bv.x, bv.y, bv.z, bv.w};
      #pragma unroll
      for (int i = 0; i < 4; i++)
        #pragma unroll
        for (int j = 0; j < 4; j++)
          acc[i][j] += ar[i] * br[j];
    }
    __syncthreads();
  }
  #pragma unroll
  for (int i = 0; i < 4; i++){
    const size_t row = (size_t)bm + ty * 4 + i;
    const float4 wh = *(const float4*)(W_hh + row * HDIM + bn + tx * 4);
    uint2 pk;
    pk.x = (unsigned)f2bf(acc[i][0] + wh.x) | ((unsigned)f2bf(acc[i][1] + wh.y) << 16);
    pk.y = (unsigned)f2bf(acc[i][2] + wh.z) | ((unsigned)f2bf(acc[i][3] + wh.w) << 16);
    *(uint2*)(Weff + row * HDIM + bn + tx * 4) = pk;
  }
}

// ---------------- per-WAVE wait on PRODUCER SUBSET: 64 slots (1 dword/lane) ----------------
// Consumer wave v consumes h[k], k in [256v,256v+256) -> produced by WGs jg in
// [16v,16v+16) x 4 reducer waves = slots [64v, 64v+64).
__device__ __forceinline__ void wait64(const unsigned* __restrict__ base, int lane, unsigned tgt){
  const unsigned* sp = base + lane;
  while (true){
    unsigned vv;
    asm volatile("global_load_dword %0, %1, off sc0 sc1\n\t"
                 "s_waitcnt vmcnt(0)"
                 : "=v"(vv) : "v"(sp) : "memory");
    if (__all((int)(vv >= tgt))) break;
    __builtin_amdgcn_s_sleep(1);
  }
}

// ---------------- persistent decoder: R10 structure + producer-subset waits ----------------
// Domain d owns batches [32d,32d+32) (2 sub-streams of 16). WG (d,jg) owns j-cols
// [16jg,16jg+16); weights in regs (wave v = k-slice [256v,256v+256)).
// Per sub-step: per-wave wait (64 producer slots) -> loads+MFMA -> sync -> exchange ->
// sync -> reduce (waves 0-3) with per-wave drain + slot post (NO trailing WG sync;
// waves 4-7 run ahead into the next sub-step, hiding reduce + load latency).
#define LDSX (16384*4 + 512*4)

template<bool RING>
__global__ void __launch_bounds__(512, 1) decoder_coop(
    const unsigned short* __restrict__ Weff_b,
    const unsigned short* __restrict__ Wout_b,
    const float* __restrict__ b_eff,
    const float* __restrict__ corr,
    const float* __restrict__ c0,
    const float* __restrict__ b_out,
    unsigned short* __restrict__ hring,  // [RING?NT+1:2][64][2048] bf16; slot0 = bf16(h0)
    unsigned* __restrict__ slots,        // [2][2][512] zeroed
    float* __restrict__ out)             // [64][512][512]
{
  extern __shared__ char smem[];
  float* exf = (float*)smem;             // 16384 floats
  float* eyf = exf + 16384;              // 512 floats
  const int bid  = blockIdx.x;
  const int d    = bid & 1;              // domain (interleaved across XCDs)
  const int jg   = bid >> 1;             // j-group 0..127
  const int tid  = threadIdx.x;
  const int v    = tid >> 6;             // wave = k-slice owner
  const int lane = tid & 63;
  const int col  = lane & 15;
  const int q    = lane >> 4;
  const int kbase = v * 256;

  // ---- A-fragment preload into regs: 4 gate tiles + y tile ----
  short8 A0[8], A1[8], A2[8], A3[8], Ay[8];
  #pragma unroll
  for (int it = 0; it < 8; ++it){
    const size_t kc = (size_t)kbase + it * 32 + q * 8;
    A0[it] = *(const short8*)(Weff_b + (size_t)(0 * HDIM + jg * 16 + col) * HDIM + kc);
    A1[it] = *(const short8*)(Weff_b + (size_t)(1 * HDIM + jg * 16 + col) * HDIM + kc);
    A2[it] = *(const short8*)(Weff_b + (size_t)(2 * HDIM + jg * 16 + col) * HDIM + kc);
    A3[it] = *(const short8*)(Weff_b + (size_t)(3 * HDIM + jg * 16 + col) * HDIM + kc);
    if (col < 4)
      Ay[it] = *(const short8*)(Wout_b + (size_t)(jg * 4 + col) * HDIM + kc);
    else { short8 z = {0,0,0,0,0,0,0,0}; Ay[it] = z; }
  }

  // ---- reducer constants: tid<256 -> (jl, bs); per-stream c-state ----
  const int jl = tid & 15;
  const int bs = tid >> 4;               // 0..15 for tid<256
  const int rj = jg * 16 + jl;
  float be0 = 0.f, be1 = 0.f, be2 = 0.f, be3 = 0.f;
  float cs_s0 = 0.f, cs_s1 = 0.f;
  if (tid < 256){
    be0 = b_eff[0 * HDIM + rj]; be1 = b_eff[1 * HDIM + rj];
    be2 = b_eff[2 * HDIM + rj]; be3 = b_eff[3 * HDIM + rj];
    cs_s0 = c0[(size_t)(d * 32 + bs) * HDIM + rj];
    cs_s1 = c0[(size_t)(d * 32 + 16 + bs) * HDIM + rj];
  }
  const bool isY = (tid >= 256 && tid < 320);
  float byo = 0.f; int yr = 0, ybs = 0;
  if (isY){ const int yt = tid - 256; yr = yt & 3; ybs = yt >> 2; byo = b_out[jg * 4 + yr]; }

  // per-lane B element-offsets per stream
  int boff[2];
  #pragma unroll
  for (int s = 0; s < 2; ++s)
    boff[s] = (d * 32 + s * 16 + col) * HDIM + kbase + q * 8;

#define WAITV(N) asm volatile("s_waitcnt vmcnt(" #N ")" ::: "memory"); __builtin_amdgcn_sched_barrier(0);
#define MFM(IT, G) { \
    const short8 bv = as8(G); \
    a0 = MF(A0[IT], bv, a0); a1 = MF(A1[IT], bv, a1); \
    a2 = MF(A2[IT], bv, a2); a3 = MF(A3[IT], bv, a3); \
    ay = MF(Ay[IT], bv, ay); }

  for (int t = 0; t < NT; ++t){
    #pragma unroll
    for (int s = 0; s < 2; ++s){
      unsigned* slot_ds = slots + (d * 2 + s) * NSLOT;
      if (t) wait64(slot_ds + 64 * v, lane, (unsigned)t);   // producer subset only

      const unsigned short* hcur = hring + (size_t)(RING ? t : (t & 1)) * NBH;
      const int bo = boff[s];
      uint32x4 G0, G1, G2, G3;
      f32x4 a0 = {0,0,0,0}, a1 = {0,0,0,0}, a2 = {0,0,0,0}, a3 = {0,0,0,0}, ay = {0,0,0,0};

      ldh<RING>(G0, hcur + bo);
      ldh<RING>(G1, hcur + bo + 32);
      ldh<RING>(G2, hcur + bo + 64);
      ldh<RING>(G3, hcur + bo + 96);
      WAITV(3) MFM(0, G0) ldh<RING>(G0, hcur + bo + 128);
      WAITV(3) MFM(1, G1) ldh<RING>(G1, hcur + bo + 160);
      WAITV(3) MFM(2, G2) ldh<RING>(G2, hcur + bo + 192);
      WAITV(3) MFM(3, G3) ldh<RING>(G3, hcur + bo + 224);
      WAITV(3) MFM(4, G0)
      WAITV(2) MFM(5, G1)
      WAITV(1) MFM(6, G2)
      WAITV(0) MFM(7, G3)

      __syncthreads();   // #1: previous sub-step's reduce done -> exf/eyf reusable

      // ---- exchange stores: pitch 32, swizzle col^((lr&7)<<2) (bijective in-row) ----
      #pragma unroll
      for (int e = 0; e < 4; ++e){
        const int lr = q * 4 + e;
        const int cx = col ^ ((lr & 7) << 2);
        exf[(v * 64 +  0 + lr) * 32 + cx] = a0[e];
        exf[(v * 64 + 16 + lr) * 32 + cx] = a1[e];
        exf[(v * 64 + 32 + lr) * 32 + cx] = a2[e];
        exf[(v * 64 + 48 + lr) * 32 + cx] = a3[e];
      }
      if (q == 0){
        #pragma unroll
        for (int e = 0; e < 4; ++e) eyf[(v * 4 + e) * 16 + col] = ay[e];
      }
      __syncthreads();   // #2: exchange visible

      if (tid < 256){
        const int cidx = bs ^ ((jl & 7) << 2);
        float gi = 0.f, gf = 0.f, gg = 0.f, go = 0.f;
        #pragma unroll
        for (int vv = 0; vv < 8; ++vv){
          gi += exf[(vv * 64 +  0 + jl) * 32 + cidx];
          gf += exf[(vv * 64 + 16 + jl) * 32 + cidx];
          gg += exf[(vv * 64 + 32 + jl) * 32 + cidx];
          go += exf[(vv * 64 + 48 + jl) * 32 + cidx];
        }
        const int b = d * 32 + s * 16 + bs;
        gi += be0; gf += be1; gg += be2; go += be3;
        if (t == 0){
          gi -= corr[(size_t)(0 * HDIM + rj) * NB + b];
          gf -= corr[(size_t)(1 * HDIM + rj) * NB + b];
          gg -= corr[(size_t)(2 * HDIM + rj) * NB + b];
          go -= corr[(size_t)(3 * HDIM + rj) * NB + b];
        }
        float cs = s ? cs_s1 : cs_s0;
        const float i_ = sigm(gi), f_ = sigm(gf), g_ = tanhfast(gg), o_ = sigm(go);
        cs = f_ * cs + i_ * g_;
        const float hn = o_ * tanhfast(cs);
        if (s) cs_s1 = cs; else cs_s0 = cs;

        // pack adjacent jl via shfl, 4B agent-scope store to IC
        const float pn = __shfl_xor(hn, 1, 64);
        unsigned short* hdst = hring + (size_t)(RING ? (t + 1) : ((t + 1) & 1)) * NBH;
        if ((jl & 1) == 0){
          const unsigned pk = (unsigned)f2bf(hn) | ((unsigned)f2bf(pn) << 16);
          __hip_atomic_store((unsigned*)(hdst + (size_t)b * HDIM + rj), pk,
                             __ATOMIC_RELAXED, __HIP_MEMORY_SCOPE_AGENT);
        }
        // per-wave arrival: own h stores drained -> post this wave's slot
        asm volatile("s_waitcnt vmcnt(0)" ::: "memory");
        __builtin_amdgcn_sched_barrier(0);
        if (lane == 0)
          __hip_atomic_store(slot_ds + (jg << 2) + v, (unsigned)(t + 1),
                             __ATOMIC_RELAXED, __HIP_MEMORY_SCOPE_AGENT);
      } else if (isY && t >= 1){
        float yv = byo;
        #pragma unroll
        for (int vv = 0; vv < 8; ++vv) yv += eyf[(vv * 4 + yr) * 16 + ybs];
        const int b = d * 32 + s * 16 + ybs;
        out[((size_t)b * NT + (t - 1)) * MEL + jg * 4 + yr] = yv;
      }
      // no trailing WG sync: non-reducer waves run ahead into the next sub-step
    }
  }

  // ---- final frame: y_511 = h_512 @ Wout^T + b_out ----
  #pragma unroll
  for (int s = 0; s < 2; ++s){
    wait64(slots + (d * 2 + s) * NSLOT + 64 * v, lane, (unsigned)NT);
    const unsigned short* hfin = hring + (size_t)(RING ? NT : 0) * NBH;  // NT even
    const int bo = boff[s];
    f32x4 ay = {0,0,0,0};
    #pragma unroll
    for (int it = 0; it < 8; ++it){
      uint32x4 g;
      ldh<RING>(g, hfin + bo + it * 32);
      asm volatile("s_waitcnt vmcnt(0)" ::: "memory");
      __builtin_amdgcn_sched_barrier(0);
      ay = MF(Ay[it], as8(g), ay);
    }
    __syncthreads();   // prior eyf readers (main loop / prev s) done
    if (q == 0){
      #pragma unroll
      for (int e = 0; e < 4; ++e) eyf[(v * 4 + e) * 16 + col] = ay[e];
    }
    __syncthreads();
    if (isY){
      float yv = byo;
      #pragma unroll
      for (int vv = 0; vv < 8; ++vv) yv += eyf[(vv * 4 + yr) * 16 + ybs];
      const int b = d * 32 + s * 16 + ybs;
      out[((size_t)b * NT + 511) * MEL + jg * 4 + yr] = yv;
    }
    __syncthreads();
  }
}

extern "C" void kernel_launch(void* const* d_in, const int* in_sizes, int n_in,
                              void* d_out, int out_size, void* d_ws, size_t ws_size,
                              hipStream_t stream){
  (void)in_sizes; (void)n_in; (void)out_size;
  const float* h0    = (const float*)d_in[1];
  const float* c0    = (const float*)d_in[2];
  const float* W_ih  = (const float*)d_in[3];
  const float* W_hh  = (const float*)d_in[4];
  const float* b_ih  = (const float*)d_in[5];
  const float* b_hh  = (const float*)d_in[6];
  const float* W_out = (const float*)d_in[7];
  const float* b_out = (const float*)d_in[8];
  float* out = (float*)d_out;

  const size_t fixed = (size_t)G4 * HDIM * 2      // weff
                     + (size_t)MEL * HDIM * 2     // wout
                     + (size_t)G4 * 4             // beff
                     + (size_t)G4 * NB * 4        // corr
                     + (size_t)NB * MEL * 4       // ym1
                     + 4 * NSLOT * sizeof(unsigned) // slots
                     + 1024;
  const bool ring = ws_size >= fixed + (size_t)(NT + 1) * NBH * 2;
  const int hslots = ring ? (NT + 1) : 2;

  char* p = (char*)d_ws;
  unsigned short* weff_b = (unsigned short*)p; p += (size_t)G4 * HDIM * 2;   // 33.5 MB
  unsigned short* wout_b = (unsigned short*)p; p += (size_t)MEL * HDIM * 2;  // 2 MB
  float* beff = (float*)p;  p += (size_t)G4 * 4;
  float* corr = (float*)p;  p += (size_t)G4 * NB * 4;                        // 2 MB
  float* ym1  = (float*)p;  p += (size_t)NB * MEL * 4;                       // 128 KB
  unsigned* slots = (unsigned*)p; p += 4 * NSLOT * sizeof(unsigned);
  unsigned short* hring = (unsigned short*)p; p += (size_t)hslots * NBH * 2;

  hipMemsetAsync(slots, 0, 4 * NSLOT * sizeof(unsigned), stream);
  convert_kernel<<<256, 256, 0, stream>>>(W_out, wout_b, MEL * HDIM / 4);
  convert_kernel<<<64, 256, 0, stream>>>(h0, hring, NBH / 4);
  beff_kernel<<<G4, 64, 0, stream>>>(W_ih, b_ih, b_hh, b_out, beff);
  ym1_kernel<<<dim3(NB, MEL / 64), 64, 0, stream>>>(W_out, h0, b_out, ym1);
  corr_kernel<<<G4, NB, 0, stream>>>(W_ih, ym1, corr);
  weff_gemm<<<dim3(HDIM / 64, G4 / 64), 256, 0, stream>>>(W_ih, W_out, W_hh, weff_b);

  void* kargs[] = { (void*)&weff_b, (void*)&wout_b, (void*)&beff, (void*)&corr,
                    (void*)&c0, (void*)&b_out, (void*)&hring, (void*)&slots, (void*)&out };
  if (ring){
    hipFuncSetAttribute((const void*)decoder_coop<true>,
                        hipFuncAttributeMaxDynamicSharedMemorySize, LDSX);
    hipLaunchCooperativeKernel((const void*)decoder_coop<true>, dim3(NWG), dim3(512),
                               kargs, LDSX, stream);
  } else {
    hipFuncSetAttribute((const void*)decoder_coop<false>,
                        hipFuncAttributeMaxDynamicSharedMemorySize, LDSX);
    hipLaunchCooperativeKernel((const void*)decoder_coop<false>, dim3(NWG), dim3(512),
                               kargs, LDSX, stream);
  }
}